// Round 1
// baseline (111.400 us; speedup 1.0000x reference)
//
#include <hip/hip_runtime.h>

// Problem constants
#define BB 32
#define CC 3
#define HH 128
#define WW 128
#define NN 1024
#define KK (CC*HH*WW)      // 49152
#define NROWS (CC*HH)      // 384 rows of length WW
#define ROWS_PER_BLK 2
#define KSPLIT (NROWS/ROWS_PER_BLK)  // 192
#define NTILE 256
#define NTILES (NN/NTILE)  // 4

// ---- setup: per-neuron normalization scale ----
// mask = g / sqrt(C*Sx*Sy) * sqrt(C*H*W)  ->  scale[n] = sqrt(H*W/(Sx*Sy))
__global__ void scale_kernel(const float* __restrict__ mu_x,
                             const float* __restrict__ mu_y,
                             const float* __restrict__ sigma_x,
                             const float* __restrict__ sigma_y,
                             float* __restrict__ scale) {
    int n = blockIdx.x * blockDim.x + threadIdx.x;
    if (n >= NN) return;
    float mux = mu_x[n], muy = mu_y[n];
    float isx = 1.0f / sigma_x[n], isy = 1.0f / sigma_y[n];
    float Sx = 0.0f, Sy = 0.0f;
    for (int i = 0; i < WW; ++i) {
        float d = (i * (1.0f/127.0f) - mux) * isx;
        Sx += __expf(-d*d);               // g^2 = exp(-r^2)
    }
    for (int i = 0; i < HH; ++i) {
        float d = (i * (1.0f/127.0f) - muy) * isy;
        Sy += __expf(-d*d);
    }
    scale[n] = sqrtf((float)(HH*WW) / (Sx * Sy));
}

// ---- transpose x[B,K] -> xT[K,B] so per-k the 32 batch values are contiguous ----
__global__ void xpose_kernel(const float* __restrict__ x, float* __restrict__ xT) {
    __shared__ float tile[64][BB + 1];
    int k0 = blockIdx.x * 64;
    int lane = threadIdx.x & 63;   // k within tile
    int bgrp = threadIdx.x >> 6;   // 0..3
#pragma unroll
    for (int i = 0; i < 8; ++i) {
        int b = bgrp * 8 + i;
        tile[lane][b] = x[(size_t)b * KK + k0 + lane];
    }
    __syncthreads();
    int b = threadIdx.x & 31;
    int kk0 = threadIdx.x >> 5;    // 0..7
#pragma unroll
    for (int i = 0; i < 8; ++i) {
        int kk = i * 8 + kk0;
        xT[(size_t)(k0 + kk) * BB + b] = tile[kk][b];
    }
}

// ---- main: out[b,n] += sum_k x[b,k] * gy[h,n]*gx[w,n]*scale[n] * weights[k,n] ----
template <bool XP>
__global__ __launch_bounds__(256) void main_kernel(
    const float* __restrict__ weights,
    const float* __restrict__ xsrc,     // xT[K,B] if XP else x[B,K]
    const float* __restrict__ mu_x, const float* __restrict__ mu_y,
    const float* __restrict__ sigma_x, const float* __restrict__ sigma_y,
    const float* __restrict__ scale,
    float* __restrict__ out) {
    const int n = blockIdx.y * NTILE + threadIdx.x;
    const int row0 = blockIdx.x * ROWS_PER_BLK;

    const float mux = mu_x[n], muy = mu_y[n];
    const float sx = sigma_x[n], sy = sigma_y[n];
    const float ax = -0.5f / (sx * sx);
    const float ay = -0.5f / (sy * sy);
    const float sc = scale[n];

    float acc[BB];
#pragma unroll
    for (int b = 0; b < BB; ++b) acc[b] = 0.0f;

    for (int r = row0; r < row0 + ROWS_PER_BLK; ++r) {
        const int h = r & (HH - 1);          // r = c*HH + h
        const float dy = h * (1.0f/127.0f) - muy;
        const float gys = __expf(ay * dy * dy) * sc;   // fold scale into gy
        const float* wrow = weights + (size_t)r * WW * NN + n;

        for (int w = 0; w < WW; ++w) {
            const float wt = wrow[(size_t)w * NN];     // coalesced across lanes
            const float dxv = w * (1.0f/127.0f) - mux;
            const float g = __expf(ax * dxv * dxv);
            const float t = gys * g * wt;

            const int k = r * WW + w;
            if constexpr (XP) {
                // wave-uniform contiguous 128B -> scalar loads
                const float4* xp4 = (const float4*)(xsrc + (size_t)k * BB);
#pragma unroll
                for (int q = 0; q < 8; ++q) {
                    float4 xv = xp4[q];
                    acc[4*q+0] = fmaf(xv.x, t, acc[4*q+0]);
                    acc[4*q+1] = fmaf(xv.y, t, acc[4*q+1]);
                    acc[4*q+2] = fmaf(xv.z, t, acc[4*q+2]);
                    acc[4*q+3] = fmaf(xv.w, t, acc[4*q+3]);
                }
            } else {
#pragma unroll
                for (int b = 0; b < BB; ++b)
                    acc[b] = fmaf(xsrc[(size_t)b * KK + k], t, acc[b]);
            }
        }
    }

    float* orow = out + n;
#pragma unroll
    for (int b = 0; b < BB; ++b)
        atomicAdd(&orow[(size_t)b * NN], acc[b]);
}

extern "C" void kernel_launch(void* const* d_in, const int* in_sizes, int n_in,
                              void* d_out, int out_size, void* d_ws, size_t ws_size,
                              hipStream_t stream) {
    const float* x       = (const float*)d_in[0];
    const float* mu_x    = (const float*)d_in[1];
    const float* mu_y    = (const float*)d_in[2];
    const float* sigma_x = (const float*)d_in[3];
    const float* sigma_y = (const float*)d_in[4];
    const float* weights = (const float*)d_in[5];
    float* out = (float*)d_out;

    float* scale = (float*)d_ws;                       // 4 KB
    float* xT    = (float*)((char*)d_ws + 4096);       // 6.3 MB
    const size_t need = 4096 + (size_t)KK * BB * sizeof(float);

    // out is accumulated atomically -> zero it every call (graph-capture safe)
    hipMemsetAsync(d_out, 0, (size_t)out_size * sizeof(float), stream);

    scale_kernel<<<(NN + 255) / 256, 256, 0, stream>>>(mu_x, mu_y, sigma_x, sigma_y, scale);

    dim3 grid(KSPLIT, NTILES);
    if (ws_size >= need) {
        xpose_kernel<<<KK / 64, 256, 0, stream>>>(x, xT);
        main_kernel<true><<<grid, 256, 0, stream>>>(weights, xT, mu_x, mu_y,
                                                    sigma_x, sigma_y, scale, out);
    } else {
        main_kernel<false><<<grid, 256, 0, stream>>>(weights, x, mu_x, mu_y,
                                                     sigma_x, sigma_y, scale, out);
    }
}